// Round 20
// baseline (374.712 us; speedup 1.0000x reference)
//
#include <hip/hip_runtime.h>

typedef unsigned short u16;
typedef _Float16 f16;
typedef _Float16 f16x8 __attribute__((ext_vector_type(8)));
typedef float f32x4 __attribute__((ext_vector_type(4)));
typedef unsigned short u16x8 __attribute__((ext_vector_type(8)));
typedef unsigned short u16x4 __attribute__((ext_vector_type(4)));

typedef __attribute__((address_space(3))) unsigned int lds_u32;
typedef __attribute__((address_space(1))) unsigned int glb_u32;

static __device__ __forceinline__ u16 f2h(float f) {
  f16 h = (f16)f;
  return __builtin_bit_cast(u16, h);
}
static __device__ __forceinline__ float h2f(u16 h) {
  return (float)__builtin_bit_cast(f16, h);
}

static __device__ __forceinline__ f32x4 mfma16h(u16x8 a, u16x8 b, f32x4 c) {
  return __builtin_amdgcn_mfma_f32_16x16x32_f16(
      __builtin_bit_cast(f16x8, a), __builtin_bit_cast(f16x8, b), c, 0, 0, 0);
}

static __device__ __forceinline__ void glds16(const u16* g, u16* l) {
  __builtin_amdgcn_global_load_lds((const glb_u32*)g, (lds_u32*)l, 16, 0, 0);
}

// stage a [128][32] u16 linear tile (512 16B-chunks) via global_load_lds, 256 threads
static __device__ __forceinline__ void glds_tile(
    const u16* __restrict__ src, int row0, int K, int k0, u16* tile, int tid) {
#pragma unroll
  for (int call = 0; call < 2; call++) {
    int c = call * 256 + tid;
    int row = c >> 2, col = (c & 3) * 8;
    glds16(&src[(size_t)(row0 + row) * K + k0 + col], tile + (size_t)(c & ~63) * 8);
  }
}

// ---------------- cos/sin tables [S][64], f64-accurate ----------------
__global__ void k_trig(float* __restrict__ cosT, float* __restrict__ sinT) {
  int idx = blockIdx.x * blockDim.x + threadIdx.x;  // S*64 threads
  int s = idx >> 6, j = idx & 63;
  double theta = exp2(-0.4152410118609203 * (double)j);  // 10000^(-j/32), f64
  double ang = (double)s * theta;
  cosT[idx] = (float)cos(ang);
  sinT[idx] = (float)sin(ang);
}

// ---------------- f32 -> fp16 hi/lo Dekker pre-split ----------------
__global__ void k_split(const float* __restrict__ src, u16* __restrict__ hi,
                        u16* __restrict__ lo, int n) {
  int i = (blockIdx.x * blockDim.x + threadIdx.x) * 4;
  if (i >= n) return;
  float4 v = *reinterpret_cast<const float4*>(src + i);
  const float* vp = reinterpret_cast<const float*>(&v);
  u16x4 hv, lv;
#pragma unroll
  for (int e = 0; e < 4; e++) {
    hv[e] = f2h(vp[e]);
    lv[e] = f2h(vp[e] - h2f(hv[e]));
  }
  *reinterpret_cast<u16x4*>(hi + i) = hv;
  *reinterpret_cast<u16x4*>(lo + i) = lv;
}

// ---------------- TN GEMM, global_load_lds staging, linear [128][32] tiles ----------------
// MODE 0: 3-pass Dekker (A hi/lo, B hi/lo pre-split fp16); rotate-scatter epilogue + lo (s<32)
// MODE 2: single-pass (A hi, B hi pre-split); scatter [BH][S][64] (V)
// MODE 3: single-pass (A=Y fp16, B hi pre-split); outF f32 row-major
template <int MODE>
__global__ __launch_bounds__(256) void k_gemm16(
    const u16* __restrict__ Ah_, const u16* __restrict__ Al_,
    const u16* __restrict__ Bh_, const u16* __restrict__ Bl_,
    int M, int N, int K,
    u16* __restrict__ outH, u16* __restrict__ loB, float* __restrict__ outF,
    const float* __restrict__ cosT, const float* __restrict__ sinT) {
  constexpr int LDT = 32;
  constexpr int NTILE = (MODE == 0) ? 4 : 2;
  __shared__ __align__(16) u16 SMEM[NTILE * 128 * 32];
  u16* Ash = SMEM;
  u16* Asl = SMEM + 4096;
  u16* Bsh = SMEM + (MODE == 0 ? 8192 : 4096);
  u16* Bsl = SMEM + 12288;
  const int tid = threadIdx.x;
  // XCD swizzle: each XCD owns 8 consecutive A row-panels (grid must be 8 x 64)
  const int lB = (int)blockIdx.y * 8 + (int)blockIdx.x;
  const int xcd = lB & 7, rr = lB >> 3;
  const int m0 = (xcd * 8 + (rr >> 3)) * 128;
  const int n0 = (rr & 7) * 128;
  const int lane = tid & 63, lr = lane & 15, lg = lane >> 4;
  const int wid = tid >> 6;
  const int wm = (wid >> 1) * 64, wn = (wid & 1) * 64;

  const f32x4 fz = {0.f, 0.f, 0.f, 0.f};
  f32x4 acc[4][4];
#pragma unroll
  for (int i = 0; i < 4; i++)
#pragma unroll
    for (int j = 0; j < 4; j++) acc[i][j] = fz;

  for (int k0 = 0; k0 < K; k0 += 32) {
    __syncthreads();
    glds_tile(Ah_, m0, K, k0, Ash, tid);
    glds_tile(Bh_, n0, K, k0, Bsh, tid);
    if constexpr (MODE == 0) {
      glds_tile(Al_, m0, K, k0, Asl, tid);
      glds_tile(Bl_, n0, K, k0, Bsl, tid);
    }
    __syncthreads();  // drains vmcnt(0) for global_load_lds

    u16x8 ah[4], al[4], bh[4], bl[4];
#pragma unroll
    for (int i = 0; i < 4; i++) {
      ah[i] = *reinterpret_cast<const u16x8*>(&Ash[(wm + i * 16 + lr) * LDT + 8 * lg]);
      if constexpr (MODE == 0)
        al[i] = *reinterpret_cast<const u16x8*>(&Asl[(wm + i * 16 + lr) * LDT + 8 * lg]);
    }
#pragma unroll
    for (int j = 0; j < 4; j++) {
      bh[j] = *reinterpret_cast<const u16x8*>(&Bsh[(wn + j * 16 + lr) * LDT + 8 * lg]);
      if constexpr (MODE == 0)
        bl[j] = *reinterpret_cast<const u16x8*>(&Bsl[(wn + j * 16 + lr) * LDT + 8 * lg]);
    }
#pragma unroll
    for (int i = 0; i < 4; i++)
#pragma unroll
      for (int j = 0; j < 4; j++) {
        acc[i][j] = mfma16h(ah[i], bh[j], acc[i][j]);
        if constexpr (MODE == 0) {
          acc[i][j] = mfma16h(ah[i], bl[j], acc[i][j]);
          acc[i][j] = mfma16h(al[i], bh[j], acc[i][j]);
        }
      }
  }

#pragma unroll
  for (int i = 0; i < 4; i++)
#pragma unroll
    for (int j = 0; j < 4; j++)
#pragma unroll
      for (int r = 0; r < 4; r++) {
        int m = m0 + wm + i * 16 + 4 * lg + r;
        int n = n0 + wn + j * 16 + lr;
        float v = acc[i][j][r];
        if constexpr (MODE == 3) {
          outF[(size_t)m * N + n] = v;
        } else {
          int b = m >> 11, s = m & 2047;  // S = 2048
          int h = n >> 6, jj = n & 63;
          if constexpr (MODE == 2) {
            outH[(((size_t)(b * 16 + h)) * 2048 + s) * 64 + jj] = f2h(v);
          } else {
            float cv = cosT[s * 64 + jj], sv = sinT[s * 64 + jj];
            float a = v * cv, bb = v * sv;
            size_t o = (((size_t)(b * 16 + h)) * 2048 + s) * 128 + jj;
            u16 ahh = f2h(a), bhh = f2h(bb);
            outH[o] = ahh;
            outH[o + 64] = bhh;
            if (s < 32) {
              size_t ol = (((size_t)(b * 16 + h)) * 32 + s) * 128 + jj;
              loB[ol] = f2h(a - h2f(ahh));
              loB[ol + 64] = f2h(bb - h2f(bhh));
            }
          }
        }
      }
}

// ---------------- V transpose: vh [BH][S][64] -> VT [BH][64][S] (validated) ----------------
__global__ __launch_bounds__(256) void k_vt(const u16* __restrict__ vh,
                                            u16* __restrict__ VT) {
  __shared__ u16 T[64][72];
  const int tid = threadIdx.x;
  const int bh = blockIdx.y, s0 = blockIdx.x * 64;
#pragma unroll
  for (int p = 0; p < 2; p++) {
    int c = p * 256 + tid;
    int r = c >> 3, j0 = (c & 7) * 8;
    *reinterpret_cast<u16x8*>(&T[r][j0]) =
        *reinterpret_cast<const u16x8*>(&vh[((size_t)bh * 2048 + s0 + r) * 64 + j0]);
  }
  __syncthreads();
#pragma unroll
  for (int p = 0; p < 2; p++) {
    int c = p * 256 + tid;
    int j = c >> 3, r0 = (c & 7) * 8;
    u16x8 o;
#pragma unroll
    for (int e = 0; e < 8; e++) o[e] = T[r0 + e][j];
    *reinterpret_cast<u16x8*>(&VT[((size_t)bh * 64 + j) * 2048 + s0 + r0]) = o;
  }
}

// ---------------- retention: QBLK=256, swapped QK^T, in-register kappa P ----------------
constexpr int LDK = 136;
constexpr int LDVT = 72;
constexpr int LDR = 65;

__global__ __launch_bounds__(1024) void k_retention(
    const u16* __restrict__ Qr, const u16* __restrict__ Kr,
    const u16* __restrict__ VT_,
    const float* __restrict__ lnw, const float* __restrict__ lnb,
    u16* __restrict__ Y) {
  // LDS: Ks 17408 | Vt 9216 = 26624; Rs (128x65x4=33280) overlays base.
  __shared__ __align__(16) char SM[33280];
  u16*   Ks  = (u16*)SM;
  u16*   Vt  = (u16*)(SM + 17408);
  float* Rs  = (float*)SM;
  __shared__ float mus[128], rstds[128];

  const int tid = threadIdx.x;
  // Balanced pairing (R19-validated): lB and lB+256 share a CU; qt pairs sum to 7.
  const int lB = blockIdx.x;            // 512 blocks
  const int half = lB >> 8;
  const int r = lB & 255;
  const int xcd = r & 7;
  const int vv = (r >> 3) & 3;
  const int w = r >> 5;
  const int bh = xcd * 8 + w;
  const int qt = half ? vv : 7 - vv;
  const int b = bh >> 4, h = bh & 15;
  const int qbase = qt * 256;
  const int wid = tid >> 6, lane = tid & 63, lr = lane & 15, lg = lane >> 4;
  const int qg = qbase + wid * 16;  // this wave's first q row
  const float lg2g = log2f(1.0f - exp2f(-5.0f - (float)h));
  // decay building blocks (all relative-safe products)
  const float gm16 = exp2f(-16.0f * lg2g);               // gamma^-16
  const float gmi  = exp2f(-lg2g);                        // gamma^-1
  const float gm4lg = exp2f(-4.0f * (float)lg * lg2g);    // gamma^(-4*lg)
  const float gm16p[4] = {1.f, gm16, gm16 * gm16, gm16 * gm16 * gm16};
  const float gmip[4]  = {1.f, gmi, gmi * gmi, gmi * gmi * gmi};

  // ---- prologue: stage Q' in four 64-row rounds through Ks, read fragments ----
  u16x8 qa[4];
#pragma unroll
  for (int hh = 0; hh < 4; hh++) {
    {
      int row = tid >> 4, col = (tid & 15) * 8;
      *reinterpret_cast<int4*>(&Ks[row * LDK + col]) =
          *reinterpret_cast<const int4*>(&Qr[((size_t)bh * 2048 + qbase + hh * 64 + row) * 128 + col]);
    }
    __syncthreads();
    if ((wid >> 2) == hh) {
      int wl = wid & 3;
#pragma unroll
      for (int dc = 0; dc < 4; dc++)
        qa[dc] = *reinterpret_cast<const u16x8*>(&Ks[(wl * 16 + lr) * LDK + dc * 32 + 8 * lg]);
    }
    __syncthreads();
  }

  const f32x4 fz = {0.f, 0.f, 0.f, 0.f};
  f32x4 oacc[4];
#pragma unroll
  for (int j = 0; j < 4; j++) oacc[j] = fz;

  const int ntiles = 4 * qt + 4;
  for (int kt = 0; kt < ntiles; ++kt) {
    const int t0 = kt * 64;
    const bool active = (t0 <= qg + 15);  // wave-uniform
    __syncthreads();  // prior tile's Ks/Vt reads done
    {
      int row = tid >> 4, col = (tid & 15) * 8;
      *reinterpret_cast<int4*>(&Ks[row * LDK + col]) =
          *reinterpret_cast<const int4*>(&Kr[((size_t)bh * 2048 + t0 + row) * 128 + col]);
    }
    if (tid < 512) {
      int j = tid >> 3, tl0 = (tid & 7) * 8;
      *reinterpret_cast<u16x8*>(&Vt[j * LDVT + tl0]) =
          *reinterpret_cast<const u16x8*>(&VT_[((size_t)bh * 64 + j) * 2048 + t0 + tl0]);
    }
    __syncthreads();

    if (active) {
      // ---- swapped QK^T: D[t][q]; lane holds t = t0+tn*16+4*lg+i, q = qg+lr ----
      const int q = qg + lr;
      const float dec_base = exp2f((float)(q - t0) * lg2g) * gm4lg;  // gamma^(q-t0-4lg)
      float pr[4][4];  // [tn][i] = decayed P[q][t]
#pragma unroll
      for (int tn = 0; tn < 4; tn++) {
        f32x4 st = fz;
#pragma unroll
        for (int dc = 0; dc < 4; dc++) {
          u16x8 kb = *reinterpret_cast<const u16x8*>(&Ks[(tn * 16 + lr) * LDK + dc * 32 + 8 * lg]);
          st = mfma16h(kb, qa[dc], st);  // A=K rows (t), B=Q cols (q)
        }
        const float dtn = dec_base * gm16p[tn];  // gamma^(q - t0 - 16tn - 4lg)
        const int tb = t0 + tn * 16 + 4 * lg;
#pragma unroll
        for (int i = 0; i < 4; i++)
          pr[tn][i] = (tb + i <= q) ? st[i] * (dtn * gmip[i]) : 0.f;
      }
      // ---- PV via kappa in-register A: kappa(lg,e) = c2*32 + (e<4 ? 4lg+e : 16+4lg+e-4) ----
#pragma unroll
      for (int c2 = 0; c2 < 2; c2++) {
        u16x8 pa = { f2h(pr[2 * c2][0]),     f2h(pr[2 * c2][1]),
                     f2h(pr[2 * c2][2]),     f2h(pr[2 * c2][3]),
                     f2h(pr[2 * c2 + 1][0]), f2h(pr[2 * c2 + 1][1]),
                     f2h(pr[2 * c2 + 1][2]), f2h(pr[2 * c2 + 1][3]) };
#pragma unroll
        for (int jn = 0; jn < 4; jn++) {
          u16x4 lo = *reinterpret_cast<const u16x4*>(&Vt[(jn * 16 + lr) * LDVT + c2 * 32 + 4 * lg]);
          u16x4 hi = *reinterpret_cast<const u16x4*>(&Vt[(jn * 16 + lr) * LDVT + c2 * 32 + 16 + 4 * lg]);
          u16x8 vb; vb.lo = lo; vb.hi = hi;
          oacc[jn] = mfma16h(pa, vb, oacc[jn]);
        }
      }
    }
  }

  // ---- epilogue: two 128-row chunks through Rs (validated pattern each) ----
#pragma unroll
  for (int ch = 0; ch < 2; ch++) {
    __syncthreads();  // Ks/Vt reads (ch0) / prior chunk stores (ch1) done
    if ((wid >> 3) == ch) {
      int wl = wid & 7;
#pragma unroll
      for (int jn = 0; jn < 4; jn++)
#pragma unroll
        for (int i = 0; i < 4; i++)
          Rs[(wl * 16 + 4 * lg + i) * LDR + jn * 16 + lr] = oacc[jn][i];
    }
    __syncthreads();
    if (tid < 128) {
      float s1 = 0.f, s2 = 0.f;
      for (int j = 0; j < 64; j++) { float v = Rs[tid * LDR + j]; s1 += v; s2 += v * v; }
      float mu = s1 * (1.f / 64.f);
      float var = s2 * (1.f / 64.f) - mu * mu;
      mus[tid] = mu; rstds[tid] = rsqrtf(var + 1e-5f);
    }
    __syncthreads();
    for (int p = tid; p < 8192; p += 1024) {
      int sl = p >> 6, j = p & 63;
      float y = (Rs[sl * LDR + j] - mus[sl]) * rstds[sl] * lnw[j] + lnb[j];
      y = y / (1.f + expf(-y));
      Y[((size_t)b * 2048 + qbase + ch * 128 + sl) * 1024 + h * 64 + j] = f2h(y);
    }
  }
}

// ---------------- f32 patch for rows s < SP, from rotated hi+lo (validated) ----------------
#define SP 32
__global__ __launch_bounds__(256) void k_patch(
    const u16* __restrict__ Qr, const u16* __restrict__ qlo,
    const u16* __restrict__ Kr, const u16* __restrict__ klo,
    const u16* __restrict__ vh_,
    const float* __restrict__ lnw, const float* __restrict__ lnb,
    u16* __restrict__ Y) {
  const int bh = blockIdx.x, b = bh >> 4, h = bh & 15;
  __shared__ float qs[SP][132], ks[SP][132];
  __shared__ float vs[SP][64], rs[SP][64];
  __shared__ float ps[SP][SP];
  __shared__ float mus[SP], rstds[SP];
  const int tid = threadIdx.x;
  const float lg2g = log2f(1.0f - exp2f(-5.0f - (float)h));

  for (int p = tid; p < SP * 128; p += 256) {
    int s = p >> 7, d = p & 127;
    size_t oh = ((size_t)bh * 2048 + s) * 128 + d;
    size_t ol = ((size_t)bh * 32 + s) * 128 + d;
    qs[s][d] = h2f(Qr[oh]) + h2f(qlo[ol]);
    ks[s][d] = h2f(Kr[oh]) + h2f(klo[ol]);
  }
  for (int p = tid; p < SP * 64; p += 256) {
    int s = p >> 6, d = p & 63;
    vs[s][d] = h2f(vh_[((size_t)bh * 2048 + s) * 64 + d]);
  }
  __syncthreads();
  for (int p = tid; p < SP * SP; p += 256) {
    int s = p / SP, t = p % SP;
    float sc = 0.f;
    if (t <= s) {
      for (int d = 0; d < 128; d += 4) {
        float4 q4 = *reinterpret_cast<const float4*>(&qs[s][d]);
        float4 k4 = *reinterpret_cast<const float4*>(&ks[t][d]);
        sc += q4.x * k4.x + q4.y * k4.y + q4.z * k4.z + q4.w * k4.w;
      }
      sc *= exp2f((float)(s - t) * lg2g);
    }
    ps[s][t] = sc;
  }
  __syncthreads();
  for (int p = tid; p < SP * 64; p += 256) {
    int s = p >> 6, j = p & 63;
    float r = 0.f;
    for (int t = 0; t <= s; t++) r += ps[s][t] * vs[t][j];
    rs[s][j] = r;
  }
  __syncthreads();
  if (tid < SP) {
    float s1 = 0.f, s2 = 0.f;
    for (int j = 0; j < 64; j++) { float v = rs[tid][j]; s1 += v; s2 += v * v; }
    float mu = s1 * (1.f / 64.f);
    float var = s2 * (1.f / 64.f) - mu * mu;
    mus[tid] = mu; rstds[tid] = rsqrtf(var + 1e-5f);
  }
  __syncthreads();
  for (int p = tid; p < SP * 64; p += 256) {
    int s = p >> 6, j = p & 63;
    float y = (rs[s][j] - mus[s]) * rstds[s] * lnw[j] + lnb[j];
    y = y / (1.f + expf(-y));
    Y[((size_t)b * 2048 + s) * 1024 + h * 64 + j] = f2h(y);
  }
}

extern "C" void kernel_launch(void* const* d_in, const int* in_sizes, int n_in,
                              void* d_out, int out_size, void* d_ws, size_t ws_size,
                              hipStream_t stream) {
  const float* x   = (const float*)d_in[0];
  const float* Wq  = (const float*)d_in[1];
  const float* Wk  = (const float*)d_in[2];
  const float* Wv  = (const float*)d_in[3];
  const float* Wo  = (const float*)d_in[4];
  const float* lnw = (const float*)d_in[5];
  const float* lnb = (const float*)d_in[6];
  float* out = (float*)d_out;

  char* ws = (char*)d_ws;
  u16*   Qr   = (u16*)(ws + 0);            // [BH][S][128] rotated fp16, 32 MB
  u16*   Kr   = (u16*)(ws + 33554432);     // 32 MB
  u16*   vh   = (u16*)(ws + 67108864);     // [BH][S][64] fp16, 16 MB
  u16*   Wqh  = (u16*)(ws + 67108864);     // Wq/Wk splits overlay vh (dead before V-GEMM)
  u16*   Wql  = (u16*)(ws + 69206016);
  u16*   Wkh  = (u16*)(ws + 71303168);
  u16*   Wkl  = (u16*)(ws + 73400320);
  u16*   xh   = (u16*)(ws + 83886080);     // fp16 hi, 16 MB (VT overlays after GEMMs)
  u16*   xl   = (u16*)(ws + 100663296);    // fp16 lo, 16 MB (Y overlays after GEMMs)
  u16*   VT   = (u16*)(ws + 83886080);
  u16*   Y    = (u16*)(ws + 100663296);
  u16*   qlo  = (u16*)(ws + 117440512);    // [BH][32][128] lo-residual
  u16*   klo  = (u16*)(ws + 117964800);
  float* cosT = (float*)(ws + 118489088);
  float* sinT = (float*)(ws + 119013376);
  u16*   Wvh  = (u16*)(ws + 119537664);    // 2 MB each
  u16*   Wvl  = (u16*)(ws + 121634816);
  u16*   Woh  = (u16*)(ws + 123731968);
  u16*   Wol  = (u16*)(ws + 125829120);
  // total 127,926,272 B

  k_trig<<<512, 256, 0, stream>>>(cosT, sinT);
  k_split<<<8192, 256, 0, stream>>>(x, xh, xl, 8388608);
  k_split<<<1024, 256, 0, stream>>>(Wq, Wqh, Wql, 1048576);
  k_split<<<1024, 256, 0, stream>>>(Wk, Wkh, Wkl, 1048576);
  k_split<<<1024, 256, 0, stream>>>(Wv, Wvh, Wvl, 1048576);
  k_split<<<1024, 256, 0, stream>>>(Wo, Woh, Wol, 1048576);

  dim3 gg(8, 64);  // N/128, M/128 (swizzled inside)
  k_gemm16<0><<<gg, 256, 0, stream>>>(xh, xl, Wqh, Wql, 8192, 1024, 1024, Qr, qlo, nullptr, cosT, sinT);
  k_gemm16<0><<<gg, 256, 0, stream>>>(xh, xl, Wkh, Wkl, 8192, 1024, 1024, Kr, klo, nullptr, cosT, sinT);
  k_gemm16<2><<<gg, 256, 0, stream>>>(xh, nullptr, Wvh, nullptr, 8192, 1024, 1024, vh, nullptr, nullptr, nullptr, nullptr);  // clobbers Wq/Wk splits (dead)

  k_vt<<<dim3(32, 64), 256, 0, stream>>>(vh, VT);   // xh dead from here

  k_retention<<<512, 1024, 0, stream>>>(Qr, Kr, VT, lnw, lnb, Y);  // xl dead from here

  k_patch<<<64, 256, 0, stream>>>(Qr, qlo, Kr, klo, vh, lnw, lnb, Y);

  k_gemm16<3><<<gg, 256, 0, stream>>>(Y, nullptr, Woh, nullptr, 8192, 1024, 1024, nullptr, nullptr, out, nullptr, nullptr);
}